// Round 7
// baseline (1168.597 us; speedup 1.0000x reference)
//
#include <hip/hip_runtime.h>

#define K_DIM 128

typedef __attribute__((ext_vector_type(8))) short short8;
typedef __attribute__((ext_vector_type(4))) float f32x4;

// ---- compile-time path tables: PATHS order = l1-major, l2, l3 ascending ----
constexpr int C_L1[34] = {0,0,0,0, 1,1,1,1,1,1,1,1,1, 2,2,2,2,2,2,2,2,2,2,2, 3,3,3,3,3,3,3,3,3,3};
constexpr int C_L2[34] = {0,1,2,3, 0,1,1,1,2,2,2,3,3, 0,1,1,1,2,2,2,2,3,3,3, 0,1,1,2,2,2,3,3,3,3};
constexpr int C_L3[34] = {0,1,2,3, 1,0,1,2,1,2,3,2,3, 2,1,2,3,0,1,2,3,1,2,3, 3,2,3,1,2,3,0,1,2,3};
constexpr int C_NP[4]  = {4,9,11,10};
constexpr int C_PL[4][11] = {
  {0,5,17,30, 0,0,0,0,0,0,0},
  {1,4,6,8,14,18,21,27,31, 0,0},
  {2,7,9,11,13,15,19,22,25,28,32},
  {3,10,12,16,20,23,24,26,29,33, 0}
};
constexpr int C_CSUM[4] = {0,8,26,48};      // 64-ch chunk base per l3
constexpr size_t FOFF[4] = {0, 1048576, 4194304, 9437184};  // per-l elem offsets
constexpr int FSZ[4] = {1048576, 3145728, 5242880, 7340032};
constexpr size_t FTOT = 16777216;           // elems per f-set

__device__ double dfactd(int n){ double r=1.0; for(int i=2;i<=n;++i) r*=(double)i; return r; }

__device__ __forceinline__ unsigned short f2bf(float x) {
    unsigned int b = __float_as_uint(x);
    return (unsigned short)((b + 0x7FFFu + ((b >> 16) & 1u)) >> 16);
}

// packed RNE f32x2 -> bf16x2 (single VALU inst; pure-ALU asm)
__device__ __forceinline__ unsigned int cvtpk(float lo, float hi) {
    unsigned int r;
    asm("v_cvt_pk_bf16_f32 %0, %1, %2" : "=v"(r) : "v"(lo), "v"(hi));
    return r;
}

// C2[p][m1i][m2i], 34*49 floats at d_ws+0
__global__ void cg_init(float* __restrict__ C2) {
    int e = blockIdx.x*blockDim.x + threadIdx.x;
    if (e >= 34*49) return;
    int p = e/49, r = e%49, m1i = r/7, m2i = r%7;
    int l1 = C_L1[p], l2 = C_L2[p], l3 = C_L3[p];
    float val = 0.f;
    if (m1i < 2*l1+1 && m2i < 2*l2+1) {
        int m1 = m1i-l1, m2 = m2i-l2, m3 = m1+m2;
        if (m3 >= -l3 && m3 <= l3) {
            double pref = sqrt((double)(2*l3+1) * dfactd(l3+l1-l2)*dfactd(l3-l1+l2)
                               * dfactd(l1+l2-l3) / dfactd(l1+l2+l3+1));
            pref *= sqrt(dfactd(l3+m3)*dfactd(l3-m3)*dfactd(l1-m1)*dfactd(l1+m1)
                         *dfactd(l2-m2)*dfactd(l2+m2));
            int kmin = max(0, max(l2-l3-m1, l1-l3+m2));
            int kmax = min(l1+l2-l3, min(l1-m1, l2+m2));
            double s = 0.0;
            for (int k=kmin;k<=kmax;++k) {
                double t = dfactd(k)*dfactd(l1+l2-l3-k)*dfactd(l1-m1-k)
                         * dfactd(l2+m2-k)*dfactd(l3-l2+m1+k)*dfactd(l3-l1-m2+k);
                s += ((k&1)? -1.0:1.0)/t;
            }
            val = (float)(pref*s);
        }
    }
    C2[e] = val;
}

// W -> bf16 transposed+swizzled tiles: chunk c: byte col*128 + (2kk ^ ((col&7)<<4))
__global__ void wt_prep(const float* __restrict__ W0, const float* __restrict__ W1,
                        const float* __restrict__ W2, const float* __restrict__ W3,
                        unsigned short* __restrict__ wt) {
    int b = blockIdx.x;
    int chunk = b >> 5;
    int e = ((b & 31) << 8) + threadIdx.x;
    int kk = e & 63, col = e >> 6;
    int l3 = (chunk < 8) ? 0 : (chunk < 26) ? 1 : (chunk < 48) ? 2 : 3;
    int local = chunk - C_CSUM[l3];
    int kin = local*64 + kk;
    const float* W = (l3==0)?W0:(l3==1)?W1:(l3==2)?W2:W3;
    float v = W[(size_t)kin*K_DIM + col];
    wt[(size_t)chunk*8192 + col*64 + (kk ^ ((col&7)<<3))] = f2bf(v);
}

// f1/f2 -> bf16 packed copies in ws
__global__ void fpack(const float* __restrict__ s0, const float* __restrict__ s1,
                      const float* __restrict__ s2, const float* __restrict__ s3,
                      const float* __restrict__ s4, const float* __restrict__ s5,
                      const float* __restrict__ s6, const float* __restrict__ s7,
                      unsigned short* __restrict__ dst) {
    int y = blockIdx.y;
    int l = y & 3, fi = y >> 2;
    const float* srcs[8] = {s0,s1,s2,s3,s4,s5,s6,s7};
    const float* src = srcs[y];
    int i4 = blockIdx.x*256 + threadIdx.x;
    if (i4*4 >= FSZ[l]) return;
    float4 v = reinterpret_cast<const float4*>(src)[i4];
    unsigned int u0 = (unsigned int)f2bf(v.x) | ((unsigned int)f2bf(v.y) << 16);
    unsigned int u1 = (unsigned int)f2bf(v.z) | ((unsigned int)f2bf(v.w) << 16);
    unsigned short* d = dst + fi*FTOT + FOFF[l] + (size_t)i4*4;
    *reinterpret_cast<uint2*>(d) = make_uint2(u0, u1);
}

#define DO_DW(i, u, v) { \
    float x0 = __uint_as_float((u)<<16); \
    float x1 = __uint_as_float((u)&0xFFFF0000u); \
    float y0 = __uint_as_float((v)<<16); \
    float y1 = __uint_as_float((v)&0xFFFF0000u); \
    a[2*(i)]   = fmaf(c*x0, y0, a[2*(i)]); \
    a[2*(i)+1] = fmaf(c*x1, y1, a[2*(i)+1]); }

// One (path, h) pair, node-aligned: stage distinct f-rows -> LDS (one coalesced
// batch), TP from LDS -> swizzled A tile, reg-staged W -> LDS, MFMA.
template<int L3, int PI>
__device__ __forceinline__ void chunk_pair(
    const unsigned short* __restrict__ f1b, const unsigned short* __restrict__ f2b,
    const unsigned short* __restrict__ wt, const float* __restrict__ C2,
    float* C2s, unsigned char* f1s, unsigned char* f2s,
    unsigned char* Asb, unsigned char* Wtb,
    int tid, int n0, int wid, int lr, int lg, f32x4 (&acc)[2*L3+1])
{
    constexpr int P  = C_PL[L3][PI];
    constexpr int l1 = C_L1[P], l2 = C_L2[P];
    constexpr int d1 = 2*l1+1, d2 = 2*l2+1;
    constexpr int TL3  = 2*L3+1;
    constexpr int ROWS = 16*TL3;          // output rows this block
    constexpr int CNT1 = 16*d1*8;         // f1 stage uint4 count (<=896)
    constexpr int CNT2 = 16*d2*8;

    if (tid < 49) C2s[tid] = C2[P*49 + tid];

    #pragma unroll
    for (int h = 0; h < 2; ++h) {
        __syncthreads();   // sync0: prev MFMA done reading LDS; C2s visible later
        // ---- one coalesced global batch: distinct f1/f2 rows + W tile ----
        const unsigned short* g1 = f1b + FOFF[l1] + (size_t)(n0*d1)*128 + h*64;
        const unsigned short* g2 = f2b + FOFF[l2] + (size_t)(n0*d2)*128 + h*64;
        uint4 v1[(CNT1+511)/512], v2[(CNT2+511)/512];
        #pragma unroll
        for (int it=0; it*512 < CNT1; ++it) { int u = tid + it*512;
            if (u < CNT1) v1[it] = *reinterpret_cast<const uint4*>(g1 + (u>>3)*128 + (u&7)*8); }
        #pragma unroll
        for (int it=0; it*512 < CNT2; ++it) { int u = tid + it*512;
            if (u < CNT2) v2[it] = *reinterpret_cast<const uint4*>(g2 + (u>>3)*128 + (u&7)*8); }
        const float4* wsrc = reinterpret_cast<const float4*>(
            wt + (size_t)(C_CSUM[L3] + PI*2 + h) * 8192);
        float4 w0 = wsrc[tid];
        float4 w1 = wsrc[tid + 512];
        // ---- f-stage LDS writes (swizzled: byte ^= (row&7)<<4) ----
        #pragma unroll
        for (int it=0; it*512 < CNT1; ++it) { int u = tid + it*512;
            if (u < CNT1) *reinterpret_cast<uint4*>(
                f1s + (u>>3)*128 + (((u&7)*16) ^ (((u>>3)&7)<<4))) = v1[it]; }
        #pragma unroll
        for (int it=0; it*512 < CNT2; ++it) { int u = tid + it*512;
            if (u < CNT2) *reinterpret_cast<uint4*>(
                f2s + (u>>3)*128 + (((u&7)*16) ^ (((u>>3)&7)<<4))) = v2[it]; }
        __syncthreads();   // sync1: f-stage visible
        // ---- TP from LDS: slot = (row, 8ch); rows*8 slots over 512 threads ----
        constexpr int SLOTS = ROWS*8;
        #pragma unroll
        for (int it=0; it*512 < SLOTS; ++it) {
            int s = tid + it*512;
            if (s < SLOTS) {
                int row = s >> 3, cho = (s & 7) << 3;   // ch base (8 bf16)
                int nl  = row / TL3;
                int m3  = row - nl*TL3 - L3;
                float a[8];
                #pragma unroll
                for (int j=0;j<8;++j) a[j] = 0.f;
                #pragma unroll
                for (int m1i=0; m1i<d1; ++m1i) {
                    int m2i = m3 + (l1 + l2) - m1i;
                    if (m2i >= 0 && m2i < d2) {
                        float c = C2s[m1i*7 + m2i];
                        if (c != 0.f) {
                            int r1 = nl*d1 + m1i;
                            int r2 = nl*d2 + m2i;
                            uint4 qa = *reinterpret_cast<const uint4*>(
                                f1s + r1*128 + ((cho*2) ^ ((r1&7)<<4)));
                            uint4 qb = *reinterpret_cast<const uint4*>(
                                f2s + r2*128 + ((cho*2) ^ ((r2&7)<<4)));
                            DO_DW(0, qa.x, qb.x)  DO_DW(1, qa.y, qb.y)
                            DO_DW(2, qa.z, qb.z)  DO_DW(3, qa.w, qb.w)
                        }
                    }
                }
                uint4 pkv = make_uint4(cvtpk(a[0],a[1]), cvtpk(a[2],a[3]),
                                       cvtpk(a[4],a[5]), cvtpk(a[6],a[7]));
                *reinterpret_cast<uint4*>(
                    Asb + row*128 + ((cho*2) ^ ((row&7)<<4))) = pkv;
            }
        }
        // ---- W LDS write (global loads had stage+TP time to land) ----
        {
            float4* dst = reinterpret_cast<float4*>(Wtb);
            dst[tid]       = w0;
            dst[tid + 512] = w1;
        }
        __syncthreads();   // sync2: A + W tiles ready
        // ---- MFMA: wave owns col-tile nt=wid; TL3 row-tiles; 2 K-steps ----
        #pragma unroll
        for (int ks=0; ks<2; ++ks) {
            const int kb  = 16*lg + 64*ks;
            const int col = 16*wid + lr;
            short8 bfr = *reinterpret_cast<const short8*>(
                Wtb + col*128 + (kb ^ ((col&7)<<4)));
            #pragma unroll
            for (int mt=0; mt<TL3; ++mt) {
                int arow = 16*mt + lr;
                short8 afr = *reinterpret_cast<const short8*>(
                    Asb + arow*128 + (kb ^ ((arow&7)<<4)));
                acc[mt] = __builtin_amdgcn_mfma_f32_16x16x32_bf16(afr, bfr, acc[mt], 0, 0, 0);
            }
        }
    }
}

template<int L3, int PI>
__device__ __forceinline__ void paths_from(
    const unsigned short* __restrict__ f1b, const unsigned short* __restrict__ f2b,
    const unsigned short* __restrict__ wt, const float* __restrict__ C2,
    float* C2s, unsigned char* f1s, unsigned char* f2s,
    unsigned char* Asb, unsigned char* Wtb,
    int tid, int n0, int wid, int lr, int lg, f32x4 (&acc)[2*L3+1])
{
    if constexpr (PI < C_NP[L3]) {
        chunk_pair<L3, PI>(f1b, f2b, wt, C2, C2s, f1s, f2s, Asb, Wtb,
                           tid, n0, wid, lr, lg, acc);
        paths_from<L3, PI+1>(f1b, f2b, wt, C2, C2s, f1s, f2s, Asb, Wtb,
                             tid, n0, wid, lr, lg, acc);
    }
}

template<int L3>
__device__ __forceinline__ void run_l3(
    int n0,
    const unsigned short* __restrict__ f1b, const unsigned short* __restrict__ f2b,
    const unsigned short* __restrict__ wt, const float* __restrict__ C2,
    float* __restrict__ out,
    float* C2s, unsigned char* f1s, unsigned char* f2s,
    unsigned char* Asb, unsigned char* Wtb)
{
    constexpr int TL3 = 2*L3+1;
    const int tid  = threadIdx.x;
    const int lane = tid & 63, wid = tid >> 6;
    const int lr   = lane & 15, lg = lane >> 4;
    constexpr size_t OB = FOFF[L3];

    f32x4 acc[TL3];
    #pragma unroll
    for (int mt=0; mt<TL3; ++mt) acc[mt] = (f32x4){0.f,0.f,0.f,0.f};

    paths_from<L3, 0>(f1b, f2b, wt, C2, C2s, f1s, f2s, Asb, Wtb,
                      tid, n0, wid, lr, lg, acc);

    // epilogue: residual (bf16 f1) + store. D: col=lane&15, row=4*(lane>>4)+i
    const unsigned short* __restrict__ fr = f1b + OB;
    #pragma unroll
    for (int mt=0; mt<TL3; ++mt) {
        #pragma unroll
        for (int i=0;i<4;++i) {
            size_t ro = (size_t)(n0*TL3 + 16*mt + 4*lg + i) * K_DIM;
            int col = 16*wid + lr;
            float res = __uint_as_float((unsigned int)fr[ro + col] << 16);
            out[OB + ro + col] = res + acc[mt][i];
        }
    }
}

__global__ __launch_bounds__(512, 5) void cg_main(
    const unsigned short* __restrict__ f1b, const unsigned short* __restrict__ f2b,
    const unsigned short* __restrict__ wt,
    const float* __restrict__ C2, float* __restrict__ out)
{
    __shared__ __align__(16) unsigned char f1s[14336];   // <=112 rows x 128B
    __shared__ __align__(16) unsigned char f2s[14336];
    __shared__ __align__(16) unsigned char Asb[14336];   // <=112 rows x 128B
    __shared__ __align__(16) unsigned char Wtb[16384];   // 128 cols x 128B
    __shared__ float C2s[49];

    // bid -> XCD x (bid&7) works node slice [x*1024,(x+1)*1024);
    // j cycles l3 (balance); 4 l3-blocks of a 16-node slice dispatch-adjacent.
    int bid = blockIdx.x;
    int x = bid & 7, j = bid >> 3;
    int l3 = j & 3, slice = j >> 2;
    int n0 = x*1024 + slice*16;
    if (l3 == 0)
        run_l3<0>(n0, f1b, f2b, wt, C2, out, C2s, f1s, f2s, Asb, Wtb);
    else if (l3 == 1)
        run_l3<1>(n0, f1b, f2b, wt, C2, out, C2s, f1s, f2s, Asb, Wtb);
    else if (l3 == 2)
        run_l3<2>(n0, f1b, f2b, wt, C2, out, C2s, f1s, f2s, Asb, Wtb);
    else
        run_l3<3>(n0, f1b, f2b, wt, C2, out, C2s, f1s, f2s, Asb, Wtb);
}

extern "C" void kernel_launch(void* const* d_in, const int* in_sizes, int n_in,
                              void* d_out, int out_size, void* d_ws, size_t ws_size,
                              hipStream_t stream) {
    const float* f10 = (const float*)d_in[0];
    const float* f20 = (const float*)d_in[1];
    const float* W0  = (const float*)d_in[2];
    const float* f11 = (const float*)d_in[3];
    const float* f21 = (const float*)d_in[4];
    const float* W1  = (const float*)d_in[5];
    const float* f12 = (const float*)d_in[6];
    const float* f22 = (const float*)d_in[7];
    const float* W2  = (const float*)d_in[8];
    const float* f13 = (const float*)d_in[9];
    const float* f23 = (const float*)d_in[10];
    const float* W3  = (const float*)d_in[11];

    float* C2 = (float*)d_ws;                                       // 6664 B
    unsigned short* wtw = (unsigned short*)((char*)d_ws + 8192);    // 1.09 MB
    unsigned short* f1b = (unsigned short*)((char*)d_ws + 1122304); // 32 MB
    unsigned short* f2b = f1b + FTOT;                               // 32 MB
    float* out = (float*)d_out;

    hipLaunchKernelGGL(cg_init, dim3(7), dim3(256), 0, stream, C2);
    hipLaunchKernelGGL(wt_prep, dim3(68*32), dim3(256), 0, stream, W0, W1, W2, W3, wtw);
    hipLaunchKernelGGL(fpack, dim3(7168, 8), dim3(256), 0, stream,
        f10, f11, f12, f13, f20, f21, f22, f23, f1b);
    hipLaunchKernelGGL(cg_main, dim3(2048), dim3(512), 0, stream,
        f1b, f2b, wtw, C2, out);
}

// Round 8
// 694.063 us; speedup vs baseline: 1.6837x; 1.6837x over previous
//
#include <hip/hip_runtime.h>

#define K_DIM 128

typedef __attribute__((ext_vector_type(8))) short short8;
typedef __attribute__((ext_vector_type(4))) float f32x4;

// ---- compile-time path tables: PATHS order = l1-major, l2, l3 ascending ----
constexpr int C_L1[34] = {0,0,0,0, 1,1,1,1,1,1,1,1,1, 2,2,2,2,2,2,2,2,2,2,2, 3,3,3,3,3,3,3,3,3,3};
constexpr int C_L2[34] = {0,1,2,3, 0,1,1,1,2,2,2,3,3, 0,1,1,1,2,2,2,2,3,3,3, 0,1,1,2,2,2,3,3,3,3};
constexpr int C_L3[34] = {0,1,2,3, 1,0,1,2,1,2,3,2,3, 2,1,2,3,0,1,2,3,1,2,3, 3,2,3,1,2,3,0,1,2,3};
constexpr int C_NP[4]  = {4,9,11,10};
constexpr int C_PL[4][11] = {
  {0,5,17,30, 0,0,0,0,0,0,0},
  {1,4,6,8,14,18,21,27,31, 0,0},
  {2,7,9,11,13,15,19,22,25,28,32},
  {3,10,12,16,20,23,24,26,29,33, 0}
};
constexpr int C_CSUM[4] = {0,8,26,48};      // 64-ch chunk base per l3
constexpr size_t FOFF[4] = {0, 1048576, 4194304, 9437184};  // per-l elem offsets
constexpr int FSZ[4] = {1048576, 3145728, 5242880, 7340032};
constexpr size_t FTOT = 16777216;           // elems per f-set

__device__ double dfactd(int n){ double r=1.0; for(int i=2;i<=n;++i) r*=(double)i; return r; }

__device__ __forceinline__ unsigned short f2bf(float x) {
    unsigned int b = __float_as_uint(x);
    return (unsigned short)((b + 0x7FFFu + ((b >> 16) & 1u)) >> 16);
}

// packed RNE f32x2 -> bf16x2 (single VALU inst; pure-ALU asm)
__device__ __forceinline__ unsigned int cvtpk(float lo, float hi) {
    unsigned int r;
    asm("v_cvt_pk_bf16_f32 %0, %1, %2" : "=v"(r) : "v"(lo), "v"(hi));
    return r;
}

// C2[p][m1i][m2i], 34*49 floats at d_ws+0
__global__ void cg_init(float* __restrict__ C2) {
    int e = blockIdx.x*blockDim.x + threadIdx.x;
    if (e >= 34*49) return;
    int p = e/49, r = e%49, m1i = r/7, m2i = r%7;
    int l1 = C_L1[p], l2 = C_L2[p], l3 = C_L3[p];
    float val = 0.f;
    if (m1i < 2*l1+1 && m2i < 2*l2+1) {
        int m1 = m1i-l1, m2 = m2i-l2, m3 = m1+m2;
        if (m3 >= -l3 && m3 <= l3) {
            double pref = sqrt((double)(2*l3+1) * dfactd(l3+l1-l2)*dfactd(l3-l1+l2)
                               * dfactd(l1+l2-l3) / dfactd(l1+l2+l3+1));
            pref *= sqrt(dfactd(l3+m3)*dfactd(l3-m3)*dfactd(l1-m1)*dfactd(l1+m1)
                         *dfactd(l2-m2)*dfactd(l2+m2));
            int kmin = max(0, max(l2-l3-m1, l1-l3+m2));
            int kmax = min(l1+l2-l3, min(l1-m1, l2+m2));
            double s = 0.0;
            for (int k=kmin;k<=kmax;++k) {
                double t = dfactd(k)*dfactd(l1+l2-l3-k)*dfactd(l1-m1-k)
                         * dfactd(l2+m2-k)*dfactd(l3-l2+m1+k)*dfactd(l3-l1-m2+k);
                s += ((k&1)? -1.0:1.0)/t;
            }
            val = (float)(pref*s);
        }
    }
    C2[e] = val;
}

// W -> bf16 transposed+swizzled tiles: chunk c: byte col*128 + (2kk ^ ((col&7)<<4))
__global__ void wt_prep(const float* __restrict__ W0, const float* __restrict__ W1,
                        const float* __restrict__ W2, const float* __restrict__ W3,
                        unsigned short* __restrict__ wt) {
    int b = blockIdx.x;
    int chunk = b >> 5;
    int e = ((b & 31) << 8) + threadIdx.x;
    int kk = e & 63, col = e >> 6;
    int l3 = (chunk < 8) ? 0 : (chunk < 26) ? 1 : (chunk < 48) ? 2 : 3;
    int local = chunk - C_CSUM[l3];
    int kin = local*64 + kk;
    const float* W = (l3==0)?W0:(l3==1)?W1:(l3==2)?W2:W3;
    float v = W[(size_t)kin*K_DIM + col];
    wt[(size_t)chunk*8192 + col*64 + (kk ^ ((col&7)<<3))] = f2bf(v);
}

// f1/f2 -> bf16 packed copies in ws
__global__ void fpack(const float* __restrict__ s0, const float* __restrict__ s1,
                      const float* __restrict__ s2, const float* __restrict__ s3,
                      const float* __restrict__ s4, const float* __restrict__ s5,
                      const float* __restrict__ s6, const float* __restrict__ s7,
                      unsigned short* __restrict__ dst) {
    int y = blockIdx.y;
    int l = y & 3, fi = y >> 2;
    const float* srcs[8] = {s0,s1,s2,s3,s4,s5,s6,s7};
    const float* src = srcs[y];
    int i4 = blockIdx.x*256 + threadIdx.x;
    if (i4*4 >= FSZ[l]) return;
    float4 v = reinterpret_cast<const float4*>(src)[i4];
    unsigned int u0 = (unsigned int)f2bf(v.x) | ((unsigned int)f2bf(v.y) << 16);
    unsigned int u1 = (unsigned int)f2bf(v.z) | ((unsigned int)f2bf(v.w) << 16);
    unsigned short* d = dst + fi*FTOT + FOFF[l] + (size_t)i4*4;
    *reinterpret_cast<uint2*>(d) = make_uint2(u0, u1);
}

#define DO_DW(i, u, v) { \
    float x0 = __uint_as_float((u)<<16); \
    float x1 = __uint_as_float((u)&0xFFFF0000u); \
    float y0 = __uint_as_float((v)<<16); \
    float y1 = __uint_as_float((v)&0xFFFF0000u); \
    a[2*(i)]   = fmaf(c*x0, y0, a[2*(i)]); \
    a[2*(i)+1] = fmaf(c*x1, y1, a[2*(i)+1]); }

// One (path, h) pair: W-load hoist, TP -> swizzled A tile, MFMA accumulate.
// 256 threads, 64 output rows per block.
template<int L3, int PI>
__device__ __forceinline__ void chunk_pair(
    const unsigned short* __restrict__ f1b, const unsigned short* __restrict__ f2b,
    const unsigned short* __restrict__ wt, const float* __restrict__ C2,
    float* C2s, unsigned char* Asb, unsigned char* Wtb,
    int tid, int n, int m3, int r, int chq,
    int wid, int lr, int lg, f32x4 (&acc)[8])
{
    constexpr int P  = C_PL[L3][PI];
    constexpr int l1 = C_L1[P], l2 = C_L2[P];
    constexpr int d1 = 2*l1+1, d2 = 2*l2+1;

    if (tid < 49) C2s[tid] = C2[P*49 + tid];

    #pragma unroll
    for (int h = 0; h < 2; ++h) {
        __syncthreads();   // prev MFMA done; C2s visible
        // ---- issue W-tile global loads early (in flight during TP) ----
        const float4* wsrc = reinterpret_cast<const float4*>(
            wt + (size_t)(C_CSUM[L3] + PI*2 + h) * 8192);
        float4 w0 = wsrc[tid];
        float4 w1 = wsrc[tid + 256];
        float4 w2 = wsrc[tid + 512];
        float4 w3 = wsrc[tid + 768];
        // ---- TP: 1 row x 16 ch per thread, fully unrolled terms ----
        float a[16];
        #pragma unroll
        for (int j=0;j<16;++j) a[j] = 0.f;
        {
            const unsigned short* bp1 = f1b + FOFF[l1] + (size_t)n*(d1*128) + h*64 + chq;
            const unsigned short* bp2 = f2b + FOFF[l2] + (size_t)n*(d2*128) + h*64 + chq;
            #pragma unroll
            for (int m1i=0; m1i<d1; ++m1i) {
                int m2i = m3 + (l1 + l2) - m1i;
                if (m2i >= 0 && m2i < d2) {
                    float c = C2s[m1i*7 + m2i];
                    uint4 qa = *reinterpret_cast<const uint4*>(bp1 + m1i*128);
                    uint4 qb = *reinterpret_cast<const uint4*>(bp1 + m1i*128 + 8);
                    uint4 ra = *reinterpret_cast<const uint4*>(bp2 + m2i*128);
                    uint4 rb = *reinterpret_cast<const uint4*>(bp2 + m2i*128 + 8);
                    DO_DW(0, qa.x, ra.x)  DO_DW(1, qa.y, ra.y)
                    DO_DW(2, qa.z, ra.z)  DO_DW(3, qa.w, ra.w)
                    DO_DW(4, qb.x, rb.x)  DO_DW(5, qb.y, rb.y)
                    DO_DW(6, qb.z, rb.z)  DO_DW(7, qb.w, rb.w)
                }
            }
        }
        // pack to bf16 (v_cvt_pk) + swizzled LDS write (2 x b128)
        unsigned int pk[8];
        #pragma unroll
        for (int j=0;j<8;++j) pk[j] = cvtpk(a[2*j], a[2*j+1]);
        {
            int ab = r*128, g0 = chq*2, key = (r&7)<<4;
            *reinterpret_cast<uint4*>(Asb + ab + ( g0        ^ key)) = make_uint4(pk[0],pk[1],pk[2],pk[3]);
            *reinterpret_cast<uint4*>(Asb + ab + ((g0 + 16)  ^ key)) = make_uint4(pk[4],pk[5],pk[6],pk[7]);
        }
        // ---- W LDS write (loads issued above have had TP to land) ----
        {
            float4* dst = reinterpret_cast<float4*>(Wtb);
            dst[tid]       = w0;
            dst[tid + 256] = w1;
            dst[tid + 512] = w2;
            dst[tid + 768] = w3;
        }
        __syncthreads();
        // ---- MFMA: 2 K=32 steps, 1 row-tile (wid) x 8 col-tiles per wave ----
        #pragma unroll
        for (int ks=0; ks<2; ++ks) {
            const int kb = 16*lg + 64*ks;
            const int arow = 16*wid + lr;
            short8 af = *reinterpret_cast<const short8*>(
                Asb + arow*128 + (kb ^ ((arow&7)<<4)));
            #pragma unroll
            for (int cc=0; cc<8; ++cc) {
                int col = 16*cc + lr;
                short8 bf = *reinterpret_cast<const short8*>(
                    Wtb + col*128 + (kb ^ ((col&7)<<4)));
                acc[cc] = __builtin_amdgcn_mfma_f32_16x16x32_bf16(af, bf, acc[cc], 0, 0, 0);
            }
        }
    }
}

template<int L3, int PI>
__device__ __forceinline__ void paths_from(
    const unsigned short* __restrict__ f1b, const unsigned short* __restrict__ f2b,
    const unsigned short* __restrict__ wt, const float* __restrict__ C2,
    float* C2s, unsigned char* Asb, unsigned char* Wtb,
    int tid, int n, int m3, int r, int chq,
    int wid, int lr, int lg, f32x4 (&acc)[8])
{
    if constexpr (PI < C_NP[L3]) {
        chunk_pair<L3, PI>(f1b, f2b, wt, C2, C2s, Asb, Wtb,
                           tid, n, m3, r, chq, wid, lr, lg, acc);
        paths_from<L3, PI+1>(f1b, f2b, wt, C2, C2s, Asb, Wtb,
                             tid, n, m3, r, chq, wid, lr, lg, acc);
    }
}

template<int L3>
__device__ __forceinline__ void run_l3(
    int rb,
    const unsigned short* __restrict__ f1b, const unsigned short* __restrict__ f2b,
    const unsigned short* __restrict__ wt, const float* __restrict__ C2,
    float* __restrict__ out,
    float* C2s, unsigned char* Asb, unsigned char* Wtb)
{
    constexpr int TL3 = 2*L3+1;
    const int tid = threadIdx.x;
    const int row0 = rb*64;
    const int r   = tid >> 2;          // TP row 0..63
    const int chq = (tid & 3) * 16;    // TP ch base within 64-half
    const int gr  = row0 + r;
    const int n   = gr / TL3;
    const int m3  = (gr - n*TL3) - L3;
    const int lane = tid & 63, wid = tid >> 6;   // wid 0..3 = row-tile
    const int lr = lane & 15, lg = lane >> 4;
    constexpr size_t OB = FOFF[L3];

    f32x4 acc[8];
    #pragma unroll
    for (int c=0;c<8;++c) acc[c] = (f32x4){0.f,0.f,0.f,0.f};

    paths_from<L3, 0>(f1b, f2b, wt, C2, C2s, Asb, Wtb,
                      tid, n, m3, r, chq, wid, lr, lg, acc);

    // epilogue: residual (bf16 f1) + store. D: col=lane&15, row=4*(lane>>4)+i
    const unsigned short* __restrict__ fr = f1b + OB;
    #pragma unroll
    for (int i=0;i<4;++i) {
        int rr = 16*wid + 4*lg + i;
        size_t ro = (size_t)(row0 + rr) * K_DIM;
        #pragma unroll
        for (int cc=0;cc<8;++cc) {
            int col = 16*cc + lr;
            float res = __uint_as_float((unsigned int)fr[ro + col] << 16);
            out[OB + ro + col] = res + acc[cc][i];
        }
    }
}

__global__ __launch_bounds__(256, 6) void cg_main(
    const unsigned short* __restrict__ f1b, const unsigned short* __restrict__ f2b,
    const unsigned short* __restrict__ wt,
    const float* __restrict__ C2, float* __restrict__ out)
{
    __shared__ __align__(16) unsigned char Asb[64*128];   // 8 KB
    __shared__ __align__(16) unsigned char Wtb[128*128];  // 16 KB
    __shared__ float C2s[49];

    // XCD-aware remap: bid%8 = XCD. Each XCD owns node slice [x*1024,(x+1)*1024)
    // for ALL l3 groups. Per-XCD 64-row block counts: {16,48,80,112}.
    int bid = blockIdx.x;
    int x = bid & 7, j = bid >> 3;
    if (j < 16)
        run_l3<0>(x*16  + j,       f1b, f2b, wt, C2, out, C2s, Asb, Wtb);
    else if (j < 64)
        run_l3<1>(x*48  + (j-16),  f1b, f2b, wt, C2, out, C2s, Asb, Wtb);
    else if (j < 144)
        run_l3<2>(x*80  + (j-64),  f1b, f2b, wt, C2, out, C2s, Asb, Wtb);
    else
        run_l3<3>(x*112 + (j-144), f1b, f2b, wt, C2, out, C2s, Asb, Wtb);
}

extern "C" void kernel_launch(void* const* d_in, const int* in_sizes, int n_in,
                              void* d_out, int out_size, void* d_ws, size_t ws_size,
                              hipStream_t stream) {
    const float* f10 = (const float*)d_in[0];
    const float* f20 = (const float*)d_in[1];
    const float* W0  = (const float*)d_in[2];
    const float* f11 = (const float*)d_in[3];
    const float* f21 = (const float*)d_in[4];
    const float* W1  = (const float*)d_in[5];
    const float* f12 = (const float*)d_in[6];
    const float* f22 = (const float*)d_in[7];
    const float* W2  = (const float*)d_in[8];
    const float* f13 = (const float*)d_in[9];
    const float* f23 = (const float*)d_in[10];
    const float* W3  = (const float*)d_in[11];

    float* C2 = (float*)d_ws;                                       // 6664 B
    unsigned short* wtw = (unsigned short*)((char*)d_ws + 8192);    // 1.09 MB
    unsigned short* f1b = (unsigned short*)((char*)d_ws + 1122304); // 32 MB
    unsigned short* f2b = f1b + FTOT;                               // 32 MB
    float* out = (float*)d_out;

    hipLaunchKernelGGL(cg_init, dim3(7), dim3(256), 0, stream, C2);
    hipLaunchKernelGGL(wt_prep, dim3(68*32), dim3(256), 0, stream, W0, W1, W2, W3, wtw);
    hipLaunchKernelGGL(fpack, dim3(7168, 8), dim3(256), 0, stream,
        f10, f11, f12, f13, f20, f21, f22, f23, f1b);
    hipLaunchKernelGGL(cg_main, dim3(2048), dim3(256), 0, stream,
        f1b, f2b, wtw, C2, out);
}

// Round 9
// 273.874 us; speedup vs baseline: 4.2669x; 2.5342x over previous
//
#include <hip/hip_runtime.h>

#define K_DIM 128

typedef __attribute__((ext_vector_type(8))) short short8;
typedef __attribute__((ext_vector_type(4))) float f32x4;

// ---- compile-time path tables: PATHS order = l1-major, l2, l3 ascending ----
constexpr int C_L1[34] = {0,0,0,0, 1,1,1,1,1,1,1,1,1, 2,2,2,2,2,2,2,2,2,2,2, 3,3,3,3,3,3,3,3,3,3};
constexpr int C_L2[34] = {0,1,2,3, 0,1,1,1,2,2,2,3,3, 0,1,1,1,2,2,2,2,3,3,3, 0,1,1,2,2,2,3,3,3,3};
constexpr int C_L3[34] = {0,1,2,3, 1,0,1,2,1,2,3,2,3, 2,1,2,3,0,1,2,3,1,2,3, 3,2,3,1,2,3,0,1,2,3};
constexpr int C_NP[4]  = {4,9,11,10};
constexpr int C_PL[4][11] = {
  {0,5,17,30, 0,0,0,0,0,0,0},
  {1,4,6,8,14,18,21,27,31, 0,0},
  {2,7,9,11,13,15,19,22,25,28,32},
  {3,10,12,16,20,23,24,26,29,33, 0}
};
constexpr int C_CSUM[4] = {0,8,26,48};      // 64-ch chunk base per l3
constexpr size_t FOFF[4] = {0, 1048576, 4194304, 9437184};  // per-l elem offsets
constexpr int FSZ[4] = {1048576, 3145728, 5242880, 7340032};
constexpr size_t FTOT = 16777216;           // elems per f-set

__device__ double dfactd(int n){ double r=1.0; for(int i=2;i<=n;++i) r*=(double)i; return r; }

__device__ __forceinline__ unsigned short f2bf(float x) {
    unsigned int b = __float_as_uint(x);
    return (unsigned short)((b + 0x7FFFu + ((b >> 16) & 1u)) >> 16);
}

// packed RNE f32x2 -> bf16x2 (single VALU inst; pure-ALU asm)
__device__ __forceinline__ unsigned int cvtpk(float lo, float hi) {
    unsigned int r;
    asm("v_cvt_pk_bf16_f32 %0, %1, %2" : "=v"(r) : "v"(lo), "v"(hi));
    return r;
}

// C2[p][m1i][m2i], 34*49 floats at d_ws+0
__global__ void cg_init(float* __restrict__ C2) {
    int e = blockIdx.x*blockDim.x + threadIdx.x;
    if (e >= 34*49) return;
    int p = e/49, r = e%49, m1i = r/7, m2i = r%7;
    int l1 = C_L1[p], l2 = C_L2[p], l3 = C_L3[p];
    float val = 0.f;
    if (m1i < 2*l1+1 && m2i < 2*l2+1) {
        int m1 = m1i-l1, m2 = m2i-l2, m3 = m1+m2;
        if (m3 >= -l3 && m3 <= l3) {
            double pref = sqrt((double)(2*l3+1) * dfactd(l3+l1-l2)*dfactd(l3-l1+l2)
                               * dfactd(l1+l2-l3) / dfactd(l1+l2+l3+1));
            pref *= sqrt(dfactd(l3+m3)*dfactd(l3-m3)*dfactd(l1-m1)*dfactd(l1+m1)
                         *dfactd(l2-m2)*dfactd(l2+m2));
            int kmin = max(0, max(l2-l3-m1, l1-l3+m2));
            int kmax = min(l1+l2-l3, min(l1-m1, l2+m2));
            double s = 0.0;
            for (int k=kmin;k<=kmax;++k) {
                double t = dfactd(k)*dfactd(l1+l2-l3-k)*dfactd(l1-m1-k)
                         * dfactd(l2+m2-k)*dfactd(l3-l2+m1+k)*dfactd(l3-l1-m2+k);
                s += ((k&1)? -1.0:1.0)/t;
            }
            val = (float)(pref*s);
        }
    }
    C2[e] = val;
}

// W -> bf16 transposed+swizzled tiles: chunk c: byte col*128 + (2kk ^ ((col&7)<<4))
__global__ void wt_prep(const float* __restrict__ W0, const float* __restrict__ W1,
                        const float* __restrict__ W2, const float* __restrict__ W3,
                        unsigned short* __restrict__ wt) {
    int b = blockIdx.x;
    int chunk = b >> 5;
    int e = ((b & 31) << 8) + threadIdx.x;
    int kk = e & 63, col = e >> 6;
    int l3 = (chunk < 8) ? 0 : (chunk < 26) ? 1 : (chunk < 48) ? 2 : 3;
    int local = chunk - C_CSUM[l3];
    int kin = local*64 + kk;
    const float* W = (l3==0)?W0:(l3==1)?W1:(l3==2)?W2:W3;
    float v = W[(size_t)kin*K_DIM + col];
    wt[(size_t)chunk*8192 + col*64 + (kk ^ ((col&7)<<3))] = f2bf(v);
}

// f1/f2 -> bf16 packed copies in ws
__global__ void fpack(const float* __restrict__ s0, const float* __restrict__ s1,
                      const float* __restrict__ s2, const float* __restrict__ s3,
                      const float* __restrict__ s4, const float* __restrict__ s5,
                      const float* __restrict__ s6, const float* __restrict__ s7,
                      unsigned short* __restrict__ dst) {
    int y = blockIdx.y;
    int l = y & 3, fi = y >> 2;
    const float* srcs[8] = {s0,s1,s2,s3,s4,s5,s6,s7};
    const float* src = srcs[y];
    int i4 = blockIdx.x*256 + threadIdx.x;
    if (i4*4 >= FSZ[l]) return;
    float4 v = reinterpret_cast<const float4*>(src)[i4];
    unsigned int u0 = (unsigned int)f2bf(v.x) | ((unsigned int)f2bf(v.y) << 16);
    unsigned int u1 = (unsigned int)f2bf(v.z) | ((unsigned int)f2bf(v.w) << 16);
    unsigned short* d = dst + fi*FTOT + FOFF[l] + (size_t)i4*4;
    *reinterpret_cast<uint2*>(d) = make_uint2(u0, u1);
}

#define DO_DW(i, u, v) { \
    float x0 = __uint_as_float((u)<<16); \
    float x1 = __uint_as_float((u)&0xFFFF0000u); \
    float y0 = __uint_as_float((v)<<16); \
    float y1 = __uint_as_float((v)&0xFFFF0000u); \
    a[2*(i)]   = fmaf(c*x0, y0, a[2*(i)]); \
    a[2*(i)+1] = fmaf(c*x1, y1, a[2*(i)+1]); }

// One (path, h) pair: W-load hoist, TP -> swizzled A tile, MFMA accumulate.
// 256 threads, 64 output rows per block.
template<int L3, int PI>
__device__ __forceinline__ void chunk_pair(
    const unsigned short* __restrict__ f1b, const unsigned short* __restrict__ f2b,
    const unsigned short* __restrict__ wt, const float* __restrict__ C2,
    float* C2s, unsigned char* Asb, unsigned char* Wtb,
    int tid, int n, int m3, int r, int chq,
    int wid, int lr, int lg, f32x4 (&acc)[8])
{
    constexpr int P  = C_PL[L3][PI];
    constexpr int l1 = C_L1[P], l2 = C_L2[P];
    constexpr int d1 = 2*l1+1, d2 = 2*l2+1;

    if (tid < 49) C2s[tid] = C2[P*49 + tid];

    #pragma unroll
    for (int h = 0; h < 2; ++h) {
        __syncthreads();   // prev MFMA done; C2s visible
        // ---- issue W-tile global loads early (in flight during TP) ----
        const float4* wsrc = reinterpret_cast<const float4*>(
            wt + (size_t)(C_CSUM[L3] + PI*2 + h) * 8192);
        float4 w0 = wsrc[tid];
        float4 w1 = wsrc[tid + 256];
        float4 w2 = wsrc[tid + 512];
        float4 w3 = wsrc[tid + 768];
        // ---- TP: 1 row x 16 ch per thread, fully unrolled terms ----
        float a[16];
        #pragma unroll
        for (int j=0;j<16;++j) a[j] = 0.f;
        {
            const unsigned short* bp1 = f1b + FOFF[l1] + (size_t)n*(d1*128) + h*64 + chq;
            const unsigned short* bp2 = f2b + FOFF[l2] + (size_t)n*(d2*128) + h*64 + chq;
            #pragma unroll
            for (int m1i=0; m1i<d1; ++m1i) {
                int m2i = m3 + (l1 + l2) - m1i;
                if (m2i >= 0 && m2i < d2) {
                    float c = C2s[m1i*7 + m2i];
                    uint4 qa = *reinterpret_cast<const uint4*>(bp1 + m1i*128);
                    uint4 qb = *reinterpret_cast<const uint4*>(bp1 + m1i*128 + 8);
                    uint4 ra = *reinterpret_cast<const uint4*>(bp2 + m2i*128);
                    uint4 rb = *reinterpret_cast<const uint4*>(bp2 + m2i*128 + 8);
                    DO_DW(0, qa.x, ra.x)  DO_DW(1, qa.y, ra.y)
                    DO_DW(2, qa.z, ra.z)  DO_DW(3, qa.w, ra.w)
                    DO_DW(4, qb.x, rb.x)  DO_DW(5, qb.y, rb.y)
                    DO_DW(6, qb.z, rb.z)  DO_DW(7, qb.w, rb.w)
                }
            }
        }
        // pack to bf16 (v_cvt_pk) + swizzled LDS write (2 x b128)
        unsigned int pk[8];
        #pragma unroll
        for (int j=0;j<8;++j) pk[j] = cvtpk(a[2*j], a[2*j+1]);
        {
            int ab = r*128, g0 = chq*2, key = (r&7)<<4;
            *reinterpret_cast<uint4*>(Asb + ab + ( g0        ^ key)) = make_uint4(pk[0],pk[1],pk[2],pk[3]);
            *reinterpret_cast<uint4*>(Asb + ab + ((g0 + 16)  ^ key)) = make_uint4(pk[4],pk[5],pk[6],pk[7]);
        }
        // ---- W LDS write (loads issued above have had TP to land) ----
        {
            float4* dst = reinterpret_cast<float4*>(Wtb);
            dst[tid]       = w0;
            dst[tid + 256] = w1;
            dst[tid + 512] = w2;
            dst[tid + 768] = w3;
        }
        __syncthreads();
        // ---- MFMA: 2 K=32 steps, 1 row-tile (wid) x 8 col-tiles per wave ----
        #pragma unroll
        for (int ks=0; ks<2; ++ks) {
            const int kb = 16*lg + 64*ks;
            const int arow = 16*wid + lr;
            short8 af = *reinterpret_cast<const short8*>(
                Asb + arow*128 + (kb ^ ((arow&7)<<4)));
            #pragma unroll
            for (int cc=0; cc<8; ++cc) {
                int col = 16*cc + lr;
                short8 bf = *reinterpret_cast<const short8*>(
                    Wtb + col*128 + (kb ^ ((col&7)<<4)));
                acc[cc] = __builtin_amdgcn_mfma_f32_16x16x32_bf16(af, bf, acc[cc], 0, 0, 0);
            }
        }
    }
}

template<int L3, int PI>
__device__ __forceinline__ void paths_from(
    const unsigned short* __restrict__ f1b, const unsigned short* __restrict__ f2b,
    const unsigned short* __restrict__ wt, const float* __restrict__ C2,
    float* C2s, unsigned char* Asb, unsigned char* Wtb,
    int tid, int n, int m3, int r, int chq,
    int wid, int lr, int lg, f32x4 (&acc)[8])
{
    if constexpr (PI < C_NP[L3]) {
        chunk_pair<L3, PI>(f1b, f2b, wt, C2, C2s, Asb, Wtb,
                           tid, n, m3, r, chq, wid, lr, lg, acc);
        paths_from<L3, PI+1>(f1b, f2b, wt, C2, C2s, Asb, Wtb,
                             tid, n, m3, r, chq, wid, lr, lg, acc);
    }
}

template<int L3>
__device__ __forceinline__ void run_l3(
    int rb,
    const unsigned short* __restrict__ f1b, const unsigned short* __restrict__ f2b,
    const unsigned short* __restrict__ wt, const float* __restrict__ C2,
    float* __restrict__ out,
    float* C2s, unsigned char* Asb, unsigned char* Wtb)
{
    constexpr int TL3 = 2*L3+1;
    const int tid = threadIdx.x;
    const int row0 = rb*64;
    const int r   = tid >> 2;          // TP row 0..63
    const int chq = (tid & 3) * 16;    // TP ch base within 64-half
    const int gr  = row0 + r;
    const int n   = gr / TL3;
    const int m3  = (gr - n*TL3) - L3;
    const int lane = tid & 63, wid = tid >> 6;   // wid 0..3 = row-tile
    const int lr = lane & 15, lg = lane >> 4;
    constexpr size_t OB = FOFF[L3];

    f32x4 acc[8];
    #pragma unroll
    for (int c=0;c<8;++c) acc[c] = (f32x4){0.f,0.f,0.f,0.f};

    paths_from<L3, 0>(f1b, f2b, wt, C2, C2s, Asb, Wtb,
                      tid, n, m3, r, chq, wid, lr, lg, acc);

    // epilogue: residual (bf16 f1) + store. D: col=lane&15, row=4*(lane>>4)+i
    const unsigned short* __restrict__ fr = f1b + OB;
    #pragma unroll
    for (int i=0;i<4;++i) {
        int rr = 16*wid + 4*lg + i;
        size_t ro = (size_t)(row0 + rr) * K_DIM;
        #pragma unroll
        for (int cc=0;cc<8;++cc) {
            int col = 16*cc + lr;
            float res = __uint_as_float((unsigned int)fr[ro + col] << 16);
            out[OB + ro + col] = res + acc[cc][i];
        }
    }
}

__global__ __launch_bounds__(256, 4) void cg_main(
    const unsigned short* __restrict__ f1b, const unsigned short* __restrict__ f2b,
    const unsigned short* __restrict__ wt,
    const float* __restrict__ C2, float* __restrict__ out)
{
    __shared__ __align__(16) unsigned char Asb[64*128];   // 8 KB
    __shared__ __align__(16) unsigned char Wtb[128*128];  // 16 KB
    __shared__ float C2s[49];

    // XCD-aware + L2-locality schedule: x = XCD, j in [0,256) per XCD.
    // 16 rounds of 16 blocks {1,3,5,7 per l3}; round r's blocks (all l3) cover
    // nodes [64r, 64r+64) of this XCD's slice -> 512KB f-data, L2-resident.
    int bid = blockIdx.x;
    int x = bid & 7, j = bid >> 3;
    int rnd = j >> 4, k = j & 15;
    if (k == 0)
        run_l3<0>(x*16  + rnd,            f1b, f2b, wt, C2, out, C2s, Asb, Wtb);
    else if (k < 4)
        run_l3<1>(x*48  + 3*rnd + (k-1),  f1b, f2b, wt, C2, out, C2s, Asb, Wtb);
    else if (k < 9)
        run_l3<2>(x*80  + 5*rnd + (k-4),  f1b, f2b, wt, C2, out, C2s, Asb, Wtb);
    else
        run_l3<3>(x*112 + 7*rnd + (k-9),  f1b, f2b, wt, C2, out, C2s, Asb, Wtb);
}

extern "C" void kernel_launch(void* const* d_in, const int* in_sizes, int n_in,
                              void* d_out, int out_size, void* d_ws, size_t ws_size,
                              hipStream_t stream) {
    const float* f10 = (const float*)d_in[0];
    const float* f20 = (const float*)d_in[1];
    const float* W0  = (const float*)d_in[2];
    const float* f11 = (const float*)d_in[3];
    const float* f21 = (const float*)d_in[4];
    const float* W1  = (const float*)d_in[5];
    const float* f12 = (const float*)d_in[6];
    const float* f22 = (const float*)d_in[7];
    const float* W2  = (const float*)d_in[8];
    const float* f13 = (const float*)d_in[9];
    const float* f23 = (const float*)d_in[10];
    const float* W3  = (const float*)d_in[11];

    float* C2 = (float*)d_ws;                                       // 6664 B
    unsigned short* wtw = (unsigned short*)((char*)d_ws + 8192);    // 1.09 MB
    unsigned short* f1b = (unsigned short*)((char*)d_ws + 1122304); // 32 MB
    unsigned short* f2b = f1b + FTOT;                               // 32 MB
    float* out = (float*)d_out;

    hipLaunchKernelGGL(cg_init, dim3(7), dim3(256), 0, stream, C2);
    hipLaunchKernelGGL(wt_prep, dim3(68*32), dim3(256), 0, stream, W0, W1, W2, W3, wtw);
    hipLaunchKernelGGL(fpack, dim3(7168, 8), dim3(256), 0, stream,
        f10, f11, f12, f13, f20, f21, f22, f23, f1b);
    hipLaunchKernelGGL(cg_main, dim3(2048), dim3(256), 0, stream,
        f1b, f2b, wtw, C2, out);
}